// Round 2
// baseline (719.896 us; speedup 1.0000x reference)
//
#include <hip/hip_runtime.h>

// BaseGNN: 2-layer GraphConv (norm='both', leaky_relu) + mean-pool rows
// [0..order] + final linear. Output: 64 floats.
//
// Round-2 structure: compaction instead of predicate-skip.
//  pass_a: E threads -> degrees, bitmap S={src|dst<=order}, compacted list2 {s,d}
//  rsqrt_compact: N threads -> inv-sqrt degs, nodelist/rank for S
//  pass_b: E threads -> compacted list1 {s, rank(d)} for dst in S
//  scatter1: grid-stride over 16*|list1| lanes -> agg1c[rank] += A[s] (atomics)
//  gemm1: grid-stride waves over |S| rows, W1 in LDS, writes h1*o_is into A
//  scatter2 / gemm2: same for layer 2 (rows <= order), then pool+final GEMV.

#define C 64
#define CAPS 32768      // max |S| rows (expected ~12.7k)
#define CAP1 524288     // max layer-1 edges (expected ~159k)
#define CAP2 65536      // max layer-2 edges (expected ~12.8k)
#define CAPR 4096       // max pooled rows (order+1 = 1024)

__global__ void k_pass_a(const int* __restrict__ src, const int* __restrict__ dst,
                         float* __restrict__ deg_out, float* __restrict__ deg_in,
                         unsigned int* __restrict__ bitmap, int* __restrict__ cnt,
                         int2* __restrict__ list2, const int* __restrict__ order_p, int E) {
    int e = blockIdx.x * blockDim.x + threadIdx.x;
    if (e >= E) return;
    int s = src[e], d = dst[e];
    atomicAdd(&deg_out[s], 1.0f);
    atomicAdd(&deg_in[d], 1.0f);
    if (d <= *order_p) {
        atomicOr(&bitmap[s >> 5], 1u << (s & 31));
        int p = atomicAdd(&cnt[1], 1);
        if (p < CAP2) list2[p] = make_int2(s, d);
    }
}

__global__ void k_rsqrt_compact(float* __restrict__ o_is, float* __restrict__ i_is,
                                const unsigned int* __restrict__ bitmap,
                                int* __restrict__ cnt, int* __restrict__ nodelist,
                                int* __restrict__ rank, int N) {
    int v = blockIdx.x * blockDim.x + threadIdx.x;
    if (v >= N) return;
    o_is[v] = rsqrtf(fmaxf(o_is[v], 1.0f));
    i_is[v] = rsqrtf(fmaxf(i_is[v], 1.0f));
    if ((bitmap[v >> 5] >> (v & 31)) & 1u) {
        int p = atomicAdd(&cnt[2], 1);
        if (p < CAPS) { nodelist[p] = v; rank[v] = p; }
        else rank[v] = -1;
    }
}

__global__ void k_scale_feat(const float* __restrict__ feat, const float* __restrict__ o_is,
                             float* __restrict__ A, int n4) {
    int i = blockIdx.x * blockDim.x + threadIdx.x;
    if (i >= n4) return;
    int node = i >> 4;
    float s = o_is[node];
    float4 v = reinterpret_cast<const float4*>(feat)[i];
    v.x *= s; v.y *= s; v.z *= s; v.w *= s;
    reinterpret_cast<float4*>(A)[i] = v;
}

__global__ void k_pass_b(const int* __restrict__ src, const int* __restrict__ dst,
                         const unsigned int* __restrict__ bitmap,
                         const int* __restrict__ rank, int* __restrict__ cnt,
                         int2* __restrict__ list1, int E) {
    int e = blockIdx.x * blockDim.x + threadIdx.x;
    if (e >= E) return;
    int d = dst[e];
    if ((bitmap[d >> 5] >> (d & 31)) & 1u) {
        int r = rank[d];
        if (r < 0) return;
        int p = atomicAdd(&cnt[0], 1);
        if (p < CAP1) list1[p] = make_int2(src[e], r);
    }
}

// agg1c[r] += A[s] over compacted list1; 16 lanes/edge, float4 atomics.
__global__ void k_scatter1(const int2* __restrict__ list1, const int* __restrict__ cnt,
                           const float* __restrict__ A, float* __restrict__ agg1c) {
    long n = (long)min(cnt[0], CAP1) * 16;
    long stride = (long)gridDim.x * blockDim.x;
    for (long idx = (long)blockIdx.x * blockDim.x + threadIdx.x; idx < n; idx += stride) {
        int i = (int)(idx >> 4), lane = (int)(idx & 15);
        int2 sr = list1[i];
        float4 v = reinterpret_cast<const float4*>(A)[sr.x * 16 + lane];
        float* a = agg1c + (size_t)sr.y * C + lane * 4;
        atomicAdd(a + 0, v.x);
        atomicAdd(a + 1, v.y);
        atomicAdd(a + 2, v.z);
        atomicAdd(a + 3, v.w);
    }
}

// agg2[d] += A[s] over compacted list2 (d <= order < CAPR).
__global__ void k_scatter2(const int2* __restrict__ list2, const int* __restrict__ cnt,
                           const float* __restrict__ A, float* __restrict__ agg2) {
    long n = (long)min(cnt[1], CAP2) * 16;
    long stride = (long)gridDim.x * blockDim.x;
    for (long idx = (long)blockIdx.x * blockDim.x + threadIdx.x; idx < n; idx += stride) {
        int i = (int)(idx >> 4), lane = (int)(idx & 15);
        int2 sd = list2[i];
        if (sd.y >= CAPR) continue;
        float4 v = reinterpret_cast<const float4*>(A)[sd.x * 16 + lane];
        float* a = agg2 + (size_t)sd.y * C + lane * 4;
        atomicAdd(a + 0, v.x);
        atomicAdd(a + 1, v.y);
        atomicAdd(a + 2, v.z);
        atomicAdd(a + 3, v.w);
    }
}

// h1 rows: A[node] = leaky(agg1c[i]@W1 * i_is + b1) * o_is, one wave per row.
__global__ void __launch_bounds__(256) k_gemm1(
        const float* __restrict__ agg1c, const float* __restrict__ W,
        const float* __restrict__ bias, const float* __restrict__ i_is,
        const float* __restrict__ o_is, const int* __restrict__ nodelist,
        const int* __restrict__ cnt, float* __restrict__ A) {
    __shared__ float Wl[C][C];
    int t = threadIdx.x;
    for (int i = t; i < C * C; i += 256) Wl[i >> 6][i & 63] = W[i];
    __syncthreads();
    int w = t >> 6, c = t & 63;
    int nS = min(cnt[2], CAPS);
    for (int i = blockIdx.x * 4 + w; i < nS; i += gridDim.x * 4) {
        int node = nodelist[i];
        const float* arow = agg1c + (size_t)i * C;
        float acc = 0.f;
#pragma unroll
        for (int k = 0; k < C; ++k) acc = fmaf(arow[k], Wl[k][c], acc);
        acc = acc * i_is[node] + bias[c];
        acc = acc > 0.f ? acc : 0.01f * acc;
        acc *= o_is[node];
        A[(size_t)node * C + c] = acc;
    }
}

// h2 rows 0..order: h2[d] = leaky(agg2[d]@W2 * i_is + b2).
__global__ void __launch_bounds__(256) k_gemm2(
        const float* __restrict__ agg2, const float* __restrict__ W,
        const float* __restrict__ bias, const float* __restrict__ i_is,
        const int* __restrict__ order_p, float* __restrict__ h2) {
    __shared__ float Wl[C][C];
    int t = threadIdx.x;
    for (int i = t; i < C * C; i += 256) Wl[i >> 6][i & 63] = W[i];
    __syncthreads();
    int w = t >> 6, c = t & 63;
    int order = *order_p;
    int last = min(order, CAPR - 1);
    for (int d = blockIdx.x * 4 + w; d <= last; d += gridDim.x * 4) {
        const float* arow = agg2 + (size_t)d * C;
        float acc = 0.f;
#pragma unroll
        for (int k = 0; k < C; ++k) acc = fmaf(arow[k], Wl[k][c], acc);
        acc = acc * i_is[d] + bias[c];
        acc = acc > 0.f ? acc : 0.01f * acc;
        h2[(size_t)d * C + c] = acc;
    }
}

__global__ void k_pool_final(const float* __restrict__ h2, const float* __restrict__ Wlin,
                             const float* __restrict__ blin, const int* __restrict__ order_p,
                             float* __restrict__ out) {
    __shared__ float partial[4][C];
    __shared__ float pooled[C];
    int t = threadIdx.x;
    int g = t >> 6, c = t & 63;
    int P = min(*order_p + 1, CAPR);
    float s = 0.f;
    for (int r = g; r < P; r += 4) s += h2[(size_t)r * C + c];
    partial[g][c] = s;
    __syncthreads();
    if (t < C) {
        float tot = partial[0][t] + partial[1][t] + partial[2][t] + partial[3][t];
        pooled[t] = tot / (float)P;
    }
    __syncthreads();
    if (t < C) {
        float acc = blin[t];
#pragma unroll
        for (int k = 0; k < C; ++k) acc = fmaf(pooled[k], Wlin[k * C + t], acc);
        out[t] = acc;
    }
}

extern "C" void kernel_launch(void* const* d_in, const int* in_sizes, int n_in,
                              void* d_out, int out_size, void* d_ws, size_t ws_size,
                              hipStream_t stream) {
    const int*   src     = (const int*)d_in[0];
    const int*   dst     = (const int*)d_in[1];
    const float* feat    = (const float*)d_in[2];
    const float* W1      = (const float*)d_in[3];
    const float* b1      = (const float*)d_in[4];
    const float* W2      = (const float*)d_in[5];
    const float* b2      = (const float*)d_in[6];
    const float* Wlin    = (const float*)d_in[7];
    const float* blin    = (const float*)d_in[8];
    const int*   order_p = (const int*)d_in[9];

    int E = in_sizes[0];
    int N = in_sizes[2] / C;
    size_t N4 = (size_t)N * 4;

    // Workspace layout
    char* ws = (char*)d_ws;
    size_t o_off    = 0;
    size_t i_off    = N4;
    size_t bm_off   = 2 * N4;
    size_t bm_bytes = (((size_t)(N + 31) / 32) * 4 + 15) & ~(size_t)15;
    size_t cnt_off  = bm_off + bm_bytes;
    size_t zero_end = cnt_off + 16;
    size_t rank_off = (zero_end + 255) & ~(size_t)255;
    size_t node_off = rank_off + N4;
    size_t l1_off   = node_off + (size_t)CAPS * 4;
    size_t l2_off   = l1_off + (size_t)CAP1 * 8;
    size_t agg1_off = (l2_off + (size_t)CAP2 * 8 + 255) & ~(size_t)255;
    size_t agg2_off = agg1_off + (size_t)CAPS * C * 4;
    size_t h2_off   = agg2_off + (size_t)CAPR * C * 4;
    size_t A_off    = h2_off + (size_t)CAPR * C * 4;
    // end = A_off + N*C*4  (~39.4 MB)

    float*        o_is   = (float*)(ws + o_off);
    float*        i_is   = (float*)(ws + i_off);
    unsigned int* bitmap = (unsigned int*)(ws + bm_off);
    int*          cnt    = (int*)(ws + cnt_off);
    int*          rank   = (int*)(ws + rank_off);
    int*          nodelist= (int*)(ws + node_off);
    int2*         list1  = (int2*)(ws + l1_off);
    int2*         list2  = (int2*)(ws + l2_off);
    float*        agg1c  = (float*)(ws + agg1_off);
    float*        agg2   = (float*)(ws + agg2_off);
    float*        h2     = (float*)(ws + h2_off);
    float*        A      = (float*)(ws + A_off);

    // zero degrees+bitmap+counters, and both agg buffers (contiguous)
    hipMemsetAsync(ws, 0, zero_end, stream);
    hipMemsetAsync(ws + agg1_off, 0, (size_t)(CAPS + CAPR) * C * 4, stream);

    k_pass_a<<<(E + 255) / 256, 256, 0, stream>>>(src, dst, o_is, i_is, bitmap, cnt, list2, order_p, E);
    k_rsqrt_compact<<<(N + 255) / 256, 256, 0, stream>>>(o_is, i_is, bitmap, cnt, nodelist, rank, N);
    k_scale_feat<<<(N * 16 + 255) / 256, 256, 0, stream>>>(feat, o_is, A, N * 16);
    k_pass_b<<<(E + 255) / 256, 256, 0, stream>>>(src, dst, bitmap, rank, cnt, list1, E);

    k_scatter1<<<1024, 256, 0, stream>>>(list1, cnt, A, agg1c);
    k_gemm1<<<512, 256, 0, stream>>>(agg1c, W1, b1, i_is, o_is, nodelist, cnt, A);

    k_scatter2<<<128, 256, 0, stream>>>(list2, cnt, A, agg2);
    k_gemm2<<<256, 256, 0, stream>>>(agg2, W2, b2, i_is, order_p, h2);

    k_pool_final<<<1, 256, 0, stream>>>(h2, Wlin, blin, order_p, (float*)d_out);
}

// Round 3
// 364.934 us; speedup vs baseline: 1.9727x; 1.9727x over previous
//
#include <hip/hip_runtime.h>

// BaseGNN: 2-layer GraphConv (norm='both', leaky_relu) + mean-pool rows
// [0..order] + final linear. Output: 64 floats.
//
// Round-3: kill single-counter atomic serialization (290us in round 2).
//  k_bitmap : E threads, bitmap S={src | dst<=order} (12.8k scattered atomicOr)
//  k_compact: N threads, wave-ballot compaction -> nodelist/rank (1 atomic/wave)
//  k_build  : two-phase block compaction -> list1{src,rank_d}, list2{rank_s,d}
//             + out-degree atomics. Only 2 global counter atomics PER BLOCK.
//  scatter1 : agg1c[rank_d] += feat[s]*rsqrt(deg_out[s]); in-deg1 counted inline
//  gemm1    : h1c[i] = leaky(agg1c@W1 * i_is + b1) * o_is   (rank-compacted)
//  scatter2 : agg2[d] += h1c[rank_s]; in-deg2 counted inline
//  gemm2    : h2[d] = leaky(agg2@W2 * i_is + b2),  d<=order
//  pool+final GEMV.

#define C 64
#define CAPS 16384      // max |S| (expected ~12.7k)
#define CAP1 262144     // max layer-1 edges (expected ~160k)
#define CAP2 32768      // max layer-2 edges (expected ~12.8k)
#define CAPR 4096       // max pooled rows (order+1 = 1024)

__global__ void k_bitmap(const int* __restrict__ src, const int* __restrict__ dst,
                         unsigned int* __restrict__ bitmap,
                         const int* __restrict__ order_p, int E) {
    int e = blockIdx.x * blockDim.x + threadIdx.x;
    if (e >= E) return;
    if (dst[e] <= *order_p) {
        int s = src[e];
        atomicOr(&bitmap[s >> 5], 1u << (s & 31));
    }
}

__global__ void k_compact(const unsigned int* __restrict__ bitmap, int* __restrict__ cnt,
                          int* __restrict__ nodelist, int* __restrict__ rank, int N) {
    int v = blockIdx.x * blockDim.x + threadIdx.x;
    bool hit = (v < N) && ((bitmap[v >> 5] >> (v & 31)) & 1u);
    unsigned long long m = __ballot(hit);
    if (m == 0ull) return;
    int lane = threadIdx.x & 63;
    int lead = __ffsll((unsigned long long)m) - 1;
    int base = 0;
    if (lane == lead) base = atomicAdd(&cnt[2], __popcll(m));
    base = __shfl(base, lead, 64);
    if (hit) {
        int p = base + __popcll(m & ((1ull << lane) - 1ull));
        if (p < CAPS) { nodelist[p] = v; rank[v] = p; }
        else rank[v] = -1;
    }
}

// Two-phase block compaction + out-degree atomics.
__global__ void __launch_bounds__(256) k_build(
        const int* __restrict__ src, const int* __restrict__ dst,
        const unsigned int* __restrict__ bitmap, const int* __restrict__ rank,
        const int* __restrict__ order_p, float* __restrict__ deg_out,
        int* __restrict__ cnt, int2* __restrict__ list1, int2* __restrict__ list2, int E) {
    __shared__ int lc1, lc2, b1s, b2s, p1, p2;
    int order = *order_p;
    long per = ((long)E + gridDim.x - 1) / gridDim.x;
    int e0 = (int)((long)blockIdx.x * per);
    int e1 = (int)min((long)E, (long)e0 + per);
    if (e0 > E) e0 = E;
    if (threadIdx.x == 0) { lc1 = 0; lc2 = 0; p1 = 0; p2 = 0; }
    __syncthreads();
    int c1 = 0, c2 = 0;
    for (int e = e0 + threadIdx.x; e < e1; e += 256) {
        int s = src[e], d = dst[e];
        atomicAdd(&deg_out[s], 1.0f);
        if (((bitmap[d >> 5] >> (d & 31)) & 1u) && rank[d] >= 0) c1++;
        if (d <= order && rank[s] >= 0) c2++;
    }
    if (c1) atomicAdd(&lc1, c1);
    if (c2) atomicAdd(&lc2, c2);
    __syncthreads();
    if (threadIdx.x == 0) {
        b1s = atomicAdd(&cnt[0], lc1);
        b2s = atomicAdd(&cnt[1], lc2);
    }
    __syncthreads();
    for (int e = e0 + threadIdx.x; e < e1; e += 256) {
        int s = src[e], d = dst[e];
        if ((bitmap[d >> 5] >> (d & 31)) & 1u) {
            int r = rank[d];
            if (r >= 0) {
                int p = b1s + atomicAdd(&p1, 1);
                if (p < CAP1) list1[p] = make_int2(s, r);
            }
        }
        if (d <= order) {
            int rs = rank[s];   // s is in S by construction of the bitmap
            if (rs >= 0) {
                int p = b2s + atomicAdd(&p2, 1);
                if (p < CAP2) list2[p] = make_int2(rs, d);
            }
        }
    }
}

// agg1c[r] += feat[s] * rsqrt(max(deg_out[s],1)); 16 lanes/edge, float4 atomics.
// lane 0 also counts in-degree of r.
__global__ void k_scatter1(const int2* __restrict__ list1, const int* __restrict__ cnt,
                           const float* __restrict__ feat, const float* __restrict__ deg_out,
                           float* __restrict__ agg1c, float* __restrict__ in1) {
    long n = (long)min(cnt[0], CAP1) * 16;
    long stride = (long)gridDim.x * blockDim.x;
    for (long idx = (long)blockIdx.x * blockDim.x + threadIdx.x; idx < n; idx += stride) {
        int i = (int)(idx >> 4), lane = (int)(idx & 15);
        int2 sr = list1[i];
        float sc = rsqrtf(fmaxf(deg_out[sr.x], 1.0f));
        float4 v = reinterpret_cast<const float4*>(feat)[(size_t)sr.x * 16 + lane];
        float* a = agg1c + (size_t)sr.y * C + lane * 4;
        atomicAdd(a + 0, v.x * sc);
        atomicAdd(a + 1, v.y * sc);
        atomicAdd(a + 2, v.z * sc);
        atomicAdd(a + 3, v.w * sc);
        if (lane == 0) atomicAdd(&in1[sr.y], 1.0f);
    }
}

// h1c[i] = leaky(agg1c[i]@W1 * rsqrt(in1[i]) + b1) * rsqrt(deg_out[node])
__global__ void __launch_bounds__(256) k_gemm1(
        const float* __restrict__ agg1c, const float* __restrict__ W,
        const float* __restrict__ bias, const float* __restrict__ in1,
        const float* __restrict__ deg_out, const int* __restrict__ nodelist,
        const int* __restrict__ cnt, float* __restrict__ h1c) {
    __shared__ float Wl[C][C];
    int t = threadIdx.x;
    for (int i = t; i < C * C; i += 256) Wl[i >> 6][i & 63] = W[i];
    __syncthreads();
    int w = t >> 6, c = t & 63;
    int nS = min(cnt[2], CAPS);
    for (int i = blockIdx.x * 4 + w; i < nS; i += gridDim.x * 4) {
        int node = nodelist[i];
        const float* arow = agg1c + (size_t)i * C;
        float acc = 0.f;
#pragma unroll
        for (int k = 0; k < C; ++k) acc = fmaf(arow[k], Wl[k][c], acc);
        acc = acc * rsqrtf(fmaxf(in1[i], 1.0f)) + bias[c];
        acc = acc > 0.f ? acc : 0.01f * acc;
        acc *= rsqrtf(fmaxf(deg_out[node], 1.0f));
        h1c[(size_t)i * C + c] = acc;
    }
}

// agg2[d] += h1c[rank_s]; lane 0 counts in-degree of d.
__global__ void k_scatter2(const int2* __restrict__ list2, const int* __restrict__ cnt,
                           const float* __restrict__ h1c, float* __restrict__ agg2,
                           float* __restrict__ in2) {
    long n = (long)min(cnt[1], CAP2) * 16;
    long stride = (long)gridDim.x * blockDim.x;
    for (long idx = (long)blockIdx.x * blockDim.x + threadIdx.x; idx < n; idx += stride) {
        int i = (int)(idx >> 4), lane = (int)(idx & 15);
        int2 rd = list2[i];
        if (rd.y >= CAPR) continue;
        float4 v = reinterpret_cast<const float4*>(h1c)[(size_t)rd.x * 16 + lane];
        float* a = agg2 + (size_t)rd.y * C + lane * 4;
        atomicAdd(a + 0, v.x);
        atomicAdd(a + 1, v.y);
        atomicAdd(a + 2, v.z);
        atomicAdd(a + 3, v.w);
        if (lane == 0) atomicAdd(&in2[rd.y], 1.0f);
    }
}

// h2[d] = leaky(agg2[d]@W2 * rsqrt(in2[d]) + b2), d = 0..order
__global__ void __launch_bounds__(256) k_gemm2(
        const float* __restrict__ agg2, const float* __restrict__ W,
        const float* __restrict__ bias, const float* __restrict__ in2,
        const int* __restrict__ order_p, float* __restrict__ h2) {
    __shared__ float Wl[C][C];
    int t = threadIdx.x;
    for (int i = t; i < C * C; i += 256) Wl[i >> 6][i & 63] = W[i];
    __syncthreads();
    int w = t >> 6, c = t & 63;
    int last = min(*order_p, CAPR - 1);
    for (int d = blockIdx.x * 4 + w; d <= last; d += gridDim.x * 4) {
        const float* arow = agg2 + (size_t)d * C;
        float acc = 0.f;
#pragma unroll
        for (int k = 0; k < C; ++k) acc = fmaf(arow[k], Wl[k][c], acc);
        acc = acc * rsqrtf(fmaxf(in2[d], 1.0f)) + bias[c];
        acc = acc > 0.f ? acc : 0.01f * acc;
        h2[(size_t)d * C + c] = acc;
    }
}

__global__ void k_pool_final(const float* __restrict__ h2, const float* __restrict__ Wlin,
                             const float* __restrict__ blin, const int* __restrict__ order_p,
                             float* __restrict__ out) {
    __shared__ float partial[4][C];
    __shared__ float pooled[C];
    int t = threadIdx.x;
    int g = t >> 6, c = t & 63;
    int P = min(*order_p + 1, CAPR);
    float s = 0.f;
    for (int r = g; r < P; r += 4) s += h2[(size_t)r * C + c];
    partial[g][c] = s;
    __syncthreads();
    if (t < C) {
        float tot = partial[0][t] + partial[1][t] + partial[2][t] + partial[3][t];
        pooled[t] = tot / (float)P;
    }
    __syncthreads();
    if (t < C) {
        float acc = blin[t];
#pragma unroll
        for (int k = 0; k < C; ++k) acc = fmaf(pooled[k], Wlin[k * C + t], acc);
        out[t] = acc;
    }
}

extern "C" void kernel_launch(void* const* d_in, const int* in_sizes, int n_in,
                              void* d_out, int out_size, void* d_ws, size_t ws_size,
                              hipStream_t stream) {
    const int*   src     = (const int*)d_in[0];
    const int*   dst     = (const int*)d_in[1];
    const float* feat    = (const float*)d_in[2];
    const float* W1      = (const float*)d_in[3];
    const float* b1      = (const float*)d_in[4];
    const float* W2      = (const float*)d_in[5];
    const float* b2      = (const float*)d_in[6];
    const float* Wlin    = (const float*)d_in[7];
    const float* blin    = (const float*)d_in[8];
    const int*   order_p = (const int*)d_in[9];

    int E = in_sizes[0];
    int N = in_sizes[2] / C;
    size_t N4 = (size_t)N * 4;

    // Workspace layout. Zeroed prefix: deg_out|bitmap|cnt|in1|in2|agg1c|agg2.
    char* ws = (char*)d_ws;
    size_t deg_off  = 0;
    size_t bm_off   = N4;
    size_t bm_bytes = (((size_t)(N + 31) / 32) * 4 + 63) & ~(size_t)63;
    size_t cnt_off  = bm_off + bm_bytes;
    size_t in1_off  = cnt_off + 64;
    size_t in2_off  = in1_off + (size_t)CAPS * 4;
    size_t agg1_off = ((in2_off + (size_t)CAPR * 4 + 255) & ~(size_t)255);
    size_t agg2_off = agg1_off + (size_t)CAPS * C * 4;
    size_t zero_end = agg2_off + (size_t)CAPR * C * 4;
    size_t rank_off = (zero_end + 255) & ~(size_t)255;
    size_t node_off = rank_off + N4;
    size_t l1_off   = node_off + (size_t)CAPS * 4;
    size_t l2_off   = l1_off + (size_t)CAP1 * 8;
    size_t h1c_off  = l2_off + (size_t)CAP2 * 8;
    size_t h2_off   = h1c_off + (size_t)CAPS * C * 4;
    // end = h2_off + CAPR*C*4  (~13 MB)

    float*        deg_out = (float*)(ws + deg_off);
    unsigned int* bitmap  = (unsigned int*)(ws + bm_off);
    int*          cnt     = (int*)(ws + cnt_off);
    float*        in1     = (float*)(ws + in1_off);
    float*        in2     = (float*)(ws + in2_off);
    float*        agg1c   = (float*)(ws + agg1_off);
    float*        agg2    = (float*)(ws + agg2_off);
    int*          rank    = (int*)(ws + rank_off);
    int*          nodelist= (int*)(ws + node_off);
    int2*         list1   = (int2*)(ws + l1_off);
    int2*         list2   = (int2*)(ws + l2_off);
    float*        h1c     = (float*)(ws + h1c_off);
    float*        h2      = (float*)(ws + h2_off);

    hipMemsetAsync(ws, 0, zero_end, stream);

    k_bitmap<<<(E + 255) / 256, 256, 0, stream>>>(src, dst, bitmap, order_p, E);
    k_compact<<<(N + 255) / 256, 256, 0, stream>>>(bitmap, cnt, nodelist, rank, N);
    k_build<<<1024, 256, 0, stream>>>(src, dst, bitmap, rank, order_p, deg_out, cnt, list1, list2, E);

    k_scatter1<<<2048, 256, 0, stream>>>(list1, cnt, feat, deg_out, agg1c, in1);
    k_gemm1<<<768, 256, 0, stream>>>(agg1c, W1, b1, in1, deg_out, nodelist, cnt, h1c);

    k_scatter2<<<128, 256, 0, stream>>>(list2, cnt, h1c, agg2, in2);
    k_gemm2<<<256, 256, 0, stream>>>(agg2, W2, b2, in2, order_p, h2);

    k_pool_final<<<1, 256, 0, stream>>>(h2, Wlin, blin, order_p, (float*)d_out);
}

// Round 4
// 204.678 us; speedup vs baseline: 3.5172x; 1.7830x over previous
//
#include <hip/hip_runtime.h>

// BaseGNN: 2-layer GraphConv (norm='both', leaky_relu) + mean-pool rows
// [0..order] + final linear. Output: 64 floats.
//
// Round-4: scatter->gather inversion. No float atomics at all.
//  pass1  : E threads: deg_out[s]++ (int), bitmap S={src|dst<=order}
//  compact: N threads, wave-ballot -> nodelist/rank
//  place  : E threads: csr1[rank(d)][*]=s (d in S), csr2[d][*]=s (d<=order);
//           fixed stride RL=64 (in-deg ~ Poisson(12.5); P(>=64) ~ 1e-20);
//           cursor counts tmp1/tmp2 double as exact in-degrees for i_is.
//  spmm1  : 1 wave / S-row: lane c: acc = sum_e feat[src][c]*rsqrt(deg_out[src]);
//           fused 64x64 GEMM via __shfl(acc,k) + W1 in LDS; epilogue folds
//           i_is, bias, leaky, next-layer o_is. Writes h1c (rank-compacted).
//  spmm2  : 1 wave / row d<=order: acc = sum_e h1c[rank[src]][c]; fused GEMM2.
//  pool+final GEMV.

#define C 64
#define CAPS 16384      // max |S| (expected ~12.7k)
#define CAPR 4096       // max pooled rows (order+1 = 1024)
#define RL 64           // fixed CSR row stride

__global__ void k_pass1(const int* __restrict__ src, const int* __restrict__ dst,
                        unsigned int* __restrict__ deg_out, unsigned int* __restrict__ bitmap,
                        const int* __restrict__ order_p, int E) {
    int e = blockIdx.x * blockDim.x + threadIdx.x;
    if (e >= E) return;
    int s = src[e];
    atomicAdd(&deg_out[s], 1u);
    if (dst[e] <= *order_p) atomicOr(&bitmap[s >> 5], 1u << (s & 31));
}

__global__ void k_compact(const unsigned int* __restrict__ bitmap, int* __restrict__ cnt,
                          int* __restrict__ nodelist, int* __restrict__ rank, int N) {
    int v = blockIdx.x * blockDim.x + threadIdx.x;
    bool hit = (v < N) && ((bitmap[v >> 5] >> (v & 31)) & 1u);
    unsigned long long m = __ballot(hit);
    if (m == 0ull) return;
    int lane = threadIdx.x & 63;
    int lead = __ffsll((unsigned long long)m) - 1;
    int base = 0;
    if (lane == lead) base = atomicAdd(&cnt[2], __popcll(m));
    base = __shfl(base, lead, 64);
    if (hit) {
        int p = base + __popcll(m & ((1ull << lane) - 1ull));
        if (p < CAPS) { nodelist[p] = v; rank[v] = p; }
        else rank[v] = -1;
    }
}

__global__ void k_place(const int* __restrict__ src, const int* __restrict__ dst,
                        const unsigned int* __restrict__ bitmap, const int* __restrict__ rank,
                        const int* __restrict__ order_p, int* __restrict__ tmp1,
                        int* __restrict__ csr1, int* __restrict__ tmp2,
                        int* __restrict__ csr2, int E) {
    int e = blockIdx.x * blockDim.x + threadIdx.x;
    if (e >= E) return;
    int order = *order_p;
    int s = src[e], d = dst[e];
    if ((bitmap[d >> 5] >> (d & 31)) & 1u) {
        int r = rank[d];
        if (r >= 0) {
            int p = atomicAdd(&tmp1[r], 1);
            if (p < RL) csr1[r * RL + p] = s;
        }
    }
    if (d <= order && d < CAPR) {
        int p = atomicAdd(&tmp2[d], 1);
        if (p < RL) csr2[d * RL + p] = s;
    }
}

// One wave per S-row: gather-aggregate + fused GEMM1.
__global__ void __launch_bounds__(256) k_spmm1(
        const int* __restrict__ csr1, const int* __restrict__ tmp1,
        const unsigned int* __restrict__ deg_out, const int* __restrict__ nodelist,
        const int* __restrict__ cnt, const float* __restrict__ feat,
        const float* __restrict__ W, const float* __restrict__ bias,
        float* __restrict__ h1c) {
    __shared__ float Wl[C * C];
    int t = threadIdx.x;
    for (int i = t; i < C * C; i += 256) Wl[i] = W[i];
    __syncthreads();
    int w = t >> 6, lane = t & 63;
    int nS = min(cnt[2], CAPS);
    for (int r = blockIdx.x * 4 + w; r < nS; r += gridDim.x * 4) {
        int lenf = tmp1[r];              // exact in-degree of this dst
        int len = min(lenf, RL);
        int s_l = 0; float sc_l = 0.f;
        if (lane < len) {
            s_l = csr1[r * RL + lane];
            sc_l = rsqrtf(fmaxf((float)deg_out[s_l], 1.f));
        }
        float acc = 0.f;
        for (int k = 0; k < len; ++k) {
            int s = __shfl(s_l, k, 64);
            float sc = __shfl(sc_l, k, 64);
            acc = fmaf(feat[(size_t)s * C + lane], sc, acc);
        }
        float h = 0.f;
#pragma unroll
        for (int k = 0; k < C; ++k) {
            float a = __shfl(acc, k, 64);
            h = fmaf(a, Wl[k * C + lane], h);
        }
        int node = nodelist[r];
        float iis = rsqrtf(fmaxf((float)lenf, 1.f));
        float ois = rsqrtf(fmaxf((float)deg_out[node], 1.f));
        h = h * iis + bias[lane];
        h = h > 0.f ? h : 0.01f * h;
        h1c[(size_t)r * C + lane] = h * ois;
    }
}

// One wave per row d<=order: gather h1c + fused GEMM2.
__global__ void __launch_bounds__(256) k_spmm2(
        const int* __restrict__ csr2, const int* __restrict__ tmp2,
        const int* __restrict__ rank, const int* __restrict__ order_p,
        const float* __restrict__ h1c, const float* __restrict__ W,
        const float* __restrict__ bias, float* __restrict__ h2) {
    __shared__ float Wl[C * C];
    int t = threadIdx.x;
    for (int i = t; i < C * C; i += 256) Wl[i] = W[i];
    __syncthreads();
    int w = t >> 6, lane = t & 63;
    int last = min(*order_p, CAPR - 1);
    for (int d = blockIdx.x * 4 + w; d <= last; d += gridDim.x * 4) {
        int lenf = tmp2[d];
        int len = min(lenf, RL);
        int rk_l = -1;
        if (lane < len) rk_l = rank[csr2[d * RL + lane]];
        float acc = 0.f;
        for (int k = 0; k < len; ++k) {
            int rk = __shfl(rk_l, k, 64);
            if (rk >= 0) acc += h1c[(size_t)rk * C + lane];
        }
        float h = 0.f;
#pragma unroll
        for (int k = 0; k < C; ++k) {
            float a = __shfl(acc, k, 64);
            h = fmaf(a, Wl[k * C + lane], h);
        }
        float iis = rsqrtf(fmaxf((float)lenf, 1.f));
        h = h * iis + bias[lane];
        h = h > 0.f ? h : 0.01f * h;
        h2[(size_t)d * C + lane] = h;
    }
}

__global__ void k_pool_final(const float* __restrict__ h2, const float* __restrict__ Wlin,
                             const float* __restrict__ blin, const int* __restrict__ order_p,
                             float* __restrict__ out) {
    __shared__ float partial[4][C];
    __shared__ float pooled[C];
    int t = threadIdx.x;
    int g = t >> 6, c = t & 63;
    int P = min(*order_p + 1, CAPR);
    float s = 0.f;
    for (int r = g; r < P; r += 4) s += h2[(size_t)r * C + c];
    partial[g][c] = s;
    __syncthreads();
    if (t < C) {
        float tot = partial[0][t] + partial[1][t] + partial[2][t] + partial[3][t];
        pooled[t] = tot / (float)P;
    }
    __syncthreads();
    if (t < C) {
        float acc = blin[t];
#pragma unroll
        for (int k = 0; k < C; ++k) acc = fmaf(pooled[k], Wlin[k * C + t], acc);
        out[t] = acc;
    }
}

extern "C" void kernel_launch(void* const* d_in, const int* in_sizes, int n_in,
                              void* d_out, int out_size, void* d_ws, size_t ws_size,
                              hipStream_t stream) {
    const int*   src     = (const int*)d_in[0];
    const int*   dst     = (const int*)d_in[1];
    const float* feat    = (const float*)d_in[2];
    const float* W1      = (const float*)d_in[3];
    const float* b1      = (const float*)d_in[4];
    const float* W2      = (const float*)d_in[5];
    const float* b2      = (const float*)d_in[6];
    const float* Wlin    = (const float*)d_in[7];
    const float* blin    = (const float*)d_in[8];
    const int*   order_p = (const int*)d_in[9];

    int E = in_sizes[0];
    int N = in_sizes[2] / C;
    size_t N4 = (size_t)N * 4;

    // Workspace layout. Zeroed prefix: deg_out | bitmap | cnt | tmp1 | tmp2.
    char* ws = (char*)d_ws;
    size_t deg_off  = 0;
    size_t bm_off   = N4;
    size_t bm_bytes = (((size_t)(N + 31) / 32) * 4 + 63) & ~(size_t)63;
    size_t cnt_off  = bm_off + bm_bytes;
    size_t tmp1_off = cnt_off + 64;
    size_t tmp2_off = tmp1_off + (size_t)CAPS * 4;
    size_t zero_end = tmp2_off + (size_t)CAPR * 4;
    size_t rank_off = (zero_end + 255) & ~(size_t)255;
    size_t node_off = rank_off + N4;
    size_t csr1_off = node_off + (size_t)CAPS * 4;
    size_t csr2_off = csr1_off + (size_t)CAPS * RL * 4;
    size_t h1c_off  = csr2_off + (size_t)CAPR * RL * 4;
    size_t h2_off   = h1c_off + (size_t)CAPS * C * 4;
    // end = h2_off + CAPR*C*4  (~11.3 MB)

    unsigned int* deg_out = (unsigned int*)(ws + deg_off);
    unsigned int* bitmap  = (unsigned int*)(ws + bm_off);
    int*          cnt     = (int*)(ws + cnt_off);
    int*          tmp1    = (int*)(ws + tmp1_off);
    int*          tmp2    = (int*)(ws + tmp2_off);
    int*          rank    = (int*)(ws + rank_off);
    int*          nodelist= (int*)(ws + node_off);
    int*          csr1    = (int*)(ws + csr1_off);
    int*          csr2    = (int*)(ws + csr2_off);
    float*        h1c     = (float*)(ws + h1c_off);
    float*        h2      = (float*)(ws + h2_off);

    hipMemsetAsync(ws, 0, zero_end, stream);

    k_pass1<<<(E + 255) / 256, 256, 0, stream>>>(src, dst, deg_out, bitmap, order_p, E);
    k_compact<<<(N + 255) / 256, 256, 0, stream>>>(bitmap, cnt, nodelist, rank, N);
    k_place<<<(E + 255) / 256, 256, 0, stream>>>(src, dst, bitmap, rank, order_p,
                                                 tmp1, csr1, tmp2, csr2, E);

    k_spmm1<<<1024, 256, 0, stream>>>(csr1, tmp1, deg_out, nodelist, cnt, feat, W1, b1, h1c);
    k_spmm2<<<256, 256, 0, stream>>>(csr2, tmp2, rank, order_p, h1c, W2, b2, h2);

    k_pool_final<<<1, 256, 0, stream>>>(h2, Wlin, blin, order_p, (float*)d_out);
}

// Round 5
// 144.879 us; speedup vs baseline: 4.9690x; 1.4128x over previous
//
#include <hip/hip_runtime.h>

// BaseGNN: 2-layer GraphConv (norm='both', leaky_relu) + mean-pool rows
// [0..order] + final linear. Output: 64 floats.
//
// Round-5: kill the single-block pooling tail (66us) + fuse.
//  pass1  : E threads: deg_out[s]++ (int), bitmap S={src|dst<=order},
//           csr2[d][*]=s placement for d<=order (no rank needed).
//  compact: N threads, wave-ballot -> nodelist/rank.
//  place1 : E threads: csr1[rank(d)][*]=s for d in S.
//  spmm1  : 1 wave/S-row: 4-way-unrolled gather of feat*rsqrt(deg_out),
//           fused 64x64 GEMM via __shfl + W1 in LDS; writes h1c.
//  spmm2p : 1 wave/row d<=order: gather h1c + fused GEMM2; h2 row kept in
//           a register and summed into LDS, one global atomicAdd(64)/block.
//           h2 never touches memory.
//  final  : tiny unrolled GEMV: out = (pooled/P) @ Wl + bl.

#define C 64
#define CAPS 16384      // max |S| (expected ~12.7k)
#define CAPR 4096       // max pooled rows (order+1 = 1024)
#define RL 64           // fixed CSR row stride (in-deg ~ Poisson(12.5))

__global__ void k_pass1(const int* __restrict__ src, const int* __restrict__ dst,
                        unsigned int* __restrict__ deg_out, unsigned int* __restrict__ bitmap,
                        int* __restrict__ tmp2, int* __restrict__ csr2,
                        const int* __restrict__ order_p, int E) {
    int e = blockIdx.x * blockDim.x + threadIdx.x;
    if (e >= E) return;
    int s = src[e], d = dst[e];
    atomicAdd(&deg_out[s], 1u);
    if (d <= *order_p) {
        atomicOr(&bitmap[s >> 5], 1u << (s & 31));
        if (d < CAPR) {
            int p = atomicAdd(&tmp2[d], 1);
            if (p < RL) csr2[d * RL + p] = s;
        }
    }
}

__global__ void k_compact(const unsigned int* __restrict__ bitmap, int* __restrict__ cnt,
                          int* __restrict__ nodelist, int* __restrict__ rank, int N) {
    int v = blockIdx.x * blockDim.x + threadIdx.x;
    bool hit = (v < N) && ((bitmap[v >> 5] >> (v & 31)) & 1u);
    unsigned long long m = __ballot(hit);
    if (m == 0ull) return;
    int lane = threadIdx.x & 63;
    int lead = __ffsll((unsigned long long)m) - 1;
    int base = 0;
    if (lane == lead) base = atomicAdd(&cnt[2], __popcll(m));
    base = __shfl(base, lead, 64);
    if (hit) {
        int p = base + __popcll(m & ((1ull << lane) - 1ull));
        if (p < CAPS) { nodelist[p] = v; rank[v] = p; }
        else rank[v] = -1;
    }
}

__global__ void k_place1(const int* __restrict__ src, const int* __restrict__ dst,
                         const unsigned int* __restrict__ bitmap, const int* __restrict__ rank,
                         int* __restrict__ tmp1, int* __restrict__ csr1, int E) {
    int e = blockIdx.x * blockDim.x + threadIdx.x;
    if (e >= E) return;
    int d = dst[e];
    if ((bitmap[d >> 5] >> (d & 31)) & 1u) {
        int r = rank[d];
        if (r >= 0) {
            int p = atomicAdd(&tmp1[r], 1);
            if (p < RL) csr1[r * RL + p] = src[e];
        }
    }
}

// One wave per S-row: unrolled gather-aggregate + fused GEMM1.
__global__ void __launch_bounds__(256) k_spmm1(
        const int* __restrict__ csr1, const int* __restrict__ tmp1,
        const unsigned int* __restrict__ deg_out, const int* __restrict__ nodelist,
        const int* __restrict__ cnt, const float* __restrict__ feat,
        const float* __restrict__ W, const float* __restrict__ bias,
        float* __restrict__ h1c) {
    __shared__ float Wl[C * C];
    int t = threadIdx.x;
    for (int i = t; i < C * C; i += 256) Wl[i] = W[i];
    __syncthreads();
    int w = t >> 6, lane = t & 63;
    int nS = min(cnt[2], CAPS);
    for (int r = blockIdx.x * 4 + w; r < nS; r += gridDim.x * 4) {
        int lenf = tmp1[r];              // exact in-degree of this dst
        int len = min(lenf, RL);
        int s_l = 0; float sc_l = 0.f;
        if (lane < len) {
            s_l = csr1[r * RL + lane];
            sc_l = rsqrtf(fmaxf((float)deg_out[s_l], 1.f));
        }
        float a0 = 0.f, a1 = 0.f, a2 = 0.f, a3 = 0.f;
        int k = 0;
        for (; k + 4 <= len; k += 4) {
            int s0 = __shfl(s_l, k, 64),     s1 = __shfl(s_l, k + 1, 64);
            int s2 = __shfl(s_l, k + 2, 64), s3 = __shfl(s_l, k + 3, 64);
            float c0 = __shfl(sc_l, k, 64),     c1 = __shfl(sc_l, k + 1, 64);
            float c2 = __shfl(sc_l, k + 2, 64), c3 = __shfl(sc_l, k + 3, 64);
            a0 = fmaf(feat[(size_t)s0 * C + lane], c0, a0);
            a1 = fmaf(feat[(size_t)s1 * C + lane], c1, a1);
            a2 = fmaf(feat[(size_t)s2 * C + lane], c2, a2);
            a3 = fmaf(feat[(size_t)s3 * C + lane], c3, a3);
        }
        for (; k < len; ++k) {
            int s = __shfl(s_l, k, 64);
            float sc = __shfl(sc_l, k, 64);
            a0 = fmaf(feat[(size_t)s * C + lane], sc, a0);
        }
        float acc = (a0 + a1) + (a2 + a3);
        float h = 0.f;
#pragma unroll
        for (int kk = 0; kk < C; ++kk) {
            float a = __shfl(acc, kk, 64);
            h = fmaf(a, Wl[kk * C + lane], h);
        }
        int node = nodelist[r];
        float iis = rsqrtf(fmaxf((float)lenf, 1.f));
        float ois = rsqrtf(fmaxf((float)deg_out[node], 1.f));
        h = h * iis + bias[lane];
        h = h > 0.f ? h : 0.01f * h;
        h1c[(size_t)r * C + lane] = h * ois;
    }
}

// One wave per row d<=order: gather h1c + fused GEMM2 + in-register pooling.
__global__ void __launch_bounds__(256) k_spmm2p(
        const int* __restrict__ csr2, const int* __restrict__ tmp2,
        const int* __restrict__ rank, const int* __restrict__ order_p,
        const float* __restrict__ h1c, const float* __restrict__ W,
        const float* __restrict__ bias, float* __restrict__ pooled) {
    __shared__ float Wl[C * C];
    __shared__ float pp[4][C];
    int t = threadIdx.x;
    for (int i = t; i < C * C; i += 256) Wl[i] = W[i];
    __syncthreads();
    int w = t >> 6, lane = t & 63;
    int last = min(*order_p, CAPR - 1);
    float psum = 0.f;
    for (int d = blockIdx.x * 4 + w; d <= last; d += gridDim.x * 4) {
        int lenf = tmp2[d];
        int len = min(lenf, RL);
        int rk_l = -1;
        if (lane < len) rk_l = rank[csr2[d * RL + lane]];
        float a0 = 0.f, a1 = 0.f, a2 = 0.f, a3 = 0.f;
        int k = 0;
        for (; k + 4 <= len; k += 4) {
            int r0 = __shfl(rk_l, k, 64),     r1 = __shfl(rk_l, k + 1, 64);
            int r2 = __shfl(rk_l, k + 2, 64), r3 = __shfl(rk_l, k + 3, 64);
            float v0 = h1c[(size_t)max(r0, 0) * C + lane];
            float v1 = h1c[(size_t)max(r1, 0) * C + lane];
            float v2 = h1c[(size_t)max(r2, 0) * C + lane];
            float v3 = h1c[(size_t)max(r3, 0) * C + lane];
            a0 += r0 >= 0 ? v0 : 0.f;
            a1 += r1 >= 0 ? v1 : 0.f;
            a2 += r2 >= 0 ? v2 : 0.f;
            a3 += r3 >= 0 ? v3 : 0.f;
        }
        for (; k < len; ++k) {
            int rk = __shfl(rk_l, k, 64);
            float v = h1c[(size_t)max(rk, 0) * C + lane];
            a0 += rk >= 0 ? v : 0.f;
        }
        float acc = (a0 + a1) + (a2 + a3);
        float h = 0.f;
#pragma unroll
        for (int kk = 0; kk < C; ++kk) {
            float a = __shfl(acc, kk, 64);
            h = fmaf(a, Wl[kk * C + lane], h);
        }
        float iis = rsqrtf(fmaxf((float)lenf, 1.f));
        h = h * iis + bias[lane];
        h = h > 0.f ? h : 0.01f * h;
        psum += h;
    }
    pp[w][lane] = psum;
    __syncthreads();
    if (t < C) {
        float tot = (pp[0][t] + pp[1][t]) + (pp[2][t] + pp[3][t]);
        atomicAdd(&pooled[t], tot);
    }
}

// out = (pooled/P) @ Wlin + blin. Tiny, fully unrolled, LDS-staged.
__global__ void k_final(const float* __restrict__ pooled, const float* __restrict__ Wlin,
                        const float* __restrict__ blin, const int* __restrict__ order_p,
                        float* __restrict__ out) {
    __shared__ float Wl[C * C];
    __shared__ float pl[C];
    int t = threadIdx.x;
    for (int i = t; i < C * C; i += 256) Wl[i] = Wlin[i];
    if (t < C) pl[t] = pooled[t] / (float)min(*order_p + 1, CAPR);
    __syncthreads();
    if (t < C) {
        float acc = blin[t];
#pragma unroll
        for (int k = 0; k < C; ++k) acc = fmaf(pl[k], Wl[k * C + t], acc);
        out[t] = acc;
    }
}

extern "C" void kernel_launch(void* const* d_in, const int* in_sizes, int n_in,
                              void* d_out, int out_size, void* d_ws, size_t ws_size,
                              hipStream_t stream) {
    const int*   src     = (const int*)d_in[0];
    const int*   dst     = (const int*)d_in[1];
    const float* feat    = (const float*)d_in[2];
    const float* W1      = (const float*)d_in[3];
    const float* b1      = (const float*)d_in[4];
    const float* W2      = (const float*)d_in[5];
    const float* b2      = (const float*)d_in[6];
    const float* Wlin    = (const float*)d_in[7];
    const float* blin    = (const float*)d_in[8];
    const int*   order_p = (const int*)d_in[9];

    int E = in_sizes[0];
    int N = in_sizes[2] / C;
    size_t N4 = (size_t)N * 4;

    // Workspace. Zeroed prefix: deg_out | bitmap | cnt | tmp1 | tmp2 | pooled.
    char* ws = (char*)d_ws;
    size_t deg_off  = 0;
    size_t bm_off   = N4;
    size_t bm_bytes = (((size_t)(N + 31) / 32) * 4 + 63) & ~(size_t)63;
    size_t cnt_off  = bm_off + bm_bytes;
    size_t tmp1_off = cnt_off + 64;
    size_t tmp2_off = tmp1_off + (size_t)CAPS * 4;
    size_t pool_off = tmp2_off + (size_t)CAPR * 4;
    size_t zero_end = pool_off + (size_t)C * 4;
    size_t rank_off = (zero_end + 255) & ~(size_t)255;
    size_t node_off = rank_off + N4;
    size_t csr1_off = node_off + (size_t)CAPS * 4;
    size_t csr2_off = csr1_off + (size_t)CAPS * RL * 4;
    size_t h1c_off  = csr2_off + (size_t)CAPR * RL * 4;
    // end = h1c_off + CAPS*C*4  (~10 MB)

    unsigned int* deg_out = (unsigned int*)(ws + deg_off);
    unsigned int* bitmap  = (unsigned int*)(ws + bm_off);
    int*          cnt     = (int*)(ws + cnt_off);
    int*          tmp1    = (int*)(ws + tmp1_off);
    int*          tmp2    = (int*)(ws + tmp2_off);
    float*        pooled  = (float*)(ws + pool_off);
    int*          rank    = (int*)(ws + rank_off);
    int*          nodelist= (int*)(ws + node_off);
    int*          csr1    = (int*)(ws + csr1_off);
    int*          csr2    = (int*)(ws + csr2_off);
    float*        h1c     = (float*)(ws + h1c_off);

    hipMemsetAsync(ws, 0, zero_end, stream);

    k_pass1<<<(E + 255) / 256, 256, 0, stream>>>(src, dst, deg_out, bitmap, tmp2, csr2, order_p, E);
    k_compact<<<(N + 255) / 256, 256, 0, stream>>>(bitmap, cnt, nodelist, rank, N);
    k_place1<<<(E + 255) / 256, 256, 0, stream>>>(src, dst, bitmap, rank, tmp1, csr1, E);

    k_spmm1<<<1024, 256, 0, stream>>>(csr1, tmp1, deg_out, nodelist, cnt, feat, W1, b1, h1c);
    k_spmm2p<<<64, 256, 0, stream>>>(csr2, tmp2, rank, order_p, h1c, W2, b2, pooled);

    k_final<<<1, 256, 0, stream>>>(pooled, Wlin, blin, order_p, (float*)d_out);
}